// Round 8
// baseline (159.628 us; speedup 1.0000x reference)
//
#include <hip/hip_runtime.h>
#include <math.h>

#define BB 4
#define NN 4096
#define CC 1024
#define HH 16
#define HD 64
#define LM 64
#define SEG 64
#define BHN (BB*HH)          // 64
#define MATP 68              // fp32 row stride (inv buffers + Erow/Prow)
#define MATE (64*MATP)

typedef __attribute__((ext_vector_type(8))) short bf16x8;
typedef __attribute__((ext_vector_type(4))) short s16x4;
typedef __attribute__((ext_vector_type(4))) float f32x4;

__device__ __forceinline__ float shfl_sum16(float v) {
  v += __shfl_xor(v, 1, 16);
  v += __shfl_xor(v, 2, 16);
  v += __shfl_xor(v, 4, 16);
  v += __shfl_xor(v, 8, 16);
  return v;
}

#define F4ADD(a, b) { (a).x += (b).x; (a).y += (b).y; (a).z += (b).z; (a).w += (b).w; }
#define RSUM16(a) { (a).x = shfl_sum16((a).x); (a).y = shfl_sum16((a).y); \
                    (a).z = shfl_sum16((a).z); (a).w = shfl_sum16((a).w); }

// split fp32 -> bf16 hi (chop) + bf16 lo (chop of residual); rel err ~2^-16
__device__ __forceinline__ void split8(const float* f, bf16x8& hi, bf16x8& lo) {
#pragma unroll
  for (int i = 0; i < 8; ++i) {
    unsigned u = __builtin_bit_cast(unsigned, f[i]);
    float hf = __builtin_bit_cast(float, u & 0xFFFF0000u);
    hi[i] = (short)(u >> 16);
    float l = f[i] - hf;
    unsigned ul = __builtin_bit_cast(unsigned, l);
    lo[i] = (short)(ul >> 16);
  }
}

__device__ __forceinline__ void split4(const float* f, s16x4& hi, s16x4& lo) {
#pragma unroll
  for (int i = 0; i < 4; ++i) {
    unsigned u = __builtin_bit_cast(unsigned, f[i]);
    float hf = __builtin_bit_cast(float, u & 0xFFFF0000u);
    hi[i] = (short)(u >> 16);
    float l = f[i] - hf;
    unsigned ul = __builtin_bit_cast(unsigned, l);
    lo[i] = (short)(ul >> 16);
  }
}

// m214-style plane: 64 rows x 64 shorts (128B rows), byte ^= (row&7)<<4.
__device__ __forceinline__ int planeAddr(int row, int cd) {
  int B = (row << 7) + (cd << 4);
  return B ^ ((row & 7) << 4);
}
__device__ __forceinline__ bf16x8 ldP(const short* __restrict__ P, int row, int cd) {
  return *(const bf16x8*)((const char*)P + planeAddr(row, cd));
}

// in-wave 4x4 transpose among lanes {l, l^16, l^32, l^48}
__device__ __forceinline__ void xpose4(float x[4], int lane) {
  bool p1 = (lane >> 4) & 1;
  float s0 = p1 ? x[0] : x[1], s1 = p1 ? x[2] : x[3];
  float r0 = __shfl_xor(s0, 16, 64), r1 = __shfl_xor(s1, 16, 64);
  if (p1) { x[0] = r0; x[2] = r1; } else { x[1] = r0; x[3] = r1; }
  bool p2 = (lane >> 5) & 1;
  s0 = p2 ? x[0] : x[2]; s1 = p2 ? x[1] : x[3];
  r0 = __shfl_xor(s0, 32, 64); r1 = __shfl_xor(s1, 32, 64);
  if (p2) { x[0] = r0; x[1] = r1; } else { x[2] = r0; x[3] = r1; }
}

// ---------------- Kernel A: Q landmark means only (K pooling folded into k3v) ----------------
__global__ __launch_bounds__(256) void lm_q_kernel(
    const float* __restrict__ Q, float* __restrict__ qlm) {
  int bh = blockIdx.y; int b = bh >> 4; int h = bh & 15;
  int tid = threadIdx.x;
  int l = blockIdx.x * 4 + (tid >> 6);
  int d = tid & 63;
  const float* qbase = Q + ((size_t)b*NN + (size_t)l*SEG)*CC + h*HD + d;
  float sq = 0.f;
#pragma unroll 8
  for (int s = 0; s < SEG; ++s) sq += qbase[(size_t)s*CC];
  qlm[(size_t)bh*4096 + l*64 + d] = sq * (1.0f/(64.0f*8.0f));  // mean then /sqrt(hd)
}

// ---------------- Kernel B: partials of kernel_3 @ V + klm pooling ----------------
// grid (32, BH): 128 n per block = 2 subs (segments) of 64. K direct-from-global.
__global__ __launch_bounds__(256, 4) void k3v_kernel(
    const float* __restrict__ K, const float* __restrict__ V,
    const float* __restrict__ qlm, float* __restrict__ klm,
    float* __restrict__ S3, float* __restrict__ ACC3) {
  __shared__ alignas(16) short VtH[64*64], VtL[64*64];  // V^T [d][n] planes (16 KB)
  __shared__ alignas(16) float Erow[64*MATP];           // E fp32 [l][n]  (17.4 KB)
  const int bh = blockIdx.y, b = bh >> 4, h = bh & 15;
  const int tile = blockIdx.x, tid = threadIdx.x;
  const int wid = tid >> 6, lane = tid & 63;
  const int lr = lane & 15, lg = lane >> 4;
  const int m0 = wid*16 + lg*4;
  const int dV = 4*lr + lg;

  // q_lm A-fragments -> registers (split once)
  bf16x8 qh[2], ql[2];
#pragma unroll
  for (int ks = 0; ks < 2; ++ks) {
    const float* qp = qlm + (size_t)bh*4096 + (wid*16 + lr)*64 + ks*32 + lg*8;
    float qf[8];
    *(float4*)&qf[0] = *(const float4*)qp;
    *(float4*)&qf[4] = *(const float4*)(qp + 4);
    split8(qf, qh[ks], ql[ks]);
  }

  f32x4 acc2[4];
#pragma unroll
  for (int t = 0; t < 4; ++t) acc2[t] = (f32x4){0.f, 0.f, 0.f, 0.f};
  float srow[4] = {0.f, 0.f, 0.f, 0.f};
  float4 gv[4];

#define K3V_VLOAD(SUB)                                                         \
  {                                                                            \
    const int n0_ = tile*128 + (SUB)*64;                                       \
    _Pragma("unroll")                                                          \
    for (int q = 0; q < 4; ++q) {                                              \
      int f = tid + 256*q;                                                     \
      int r = f >> 4, c4 = (f & 15) << 2;                                      \
      gv[q] = *(const float4*)&V[((size_t)b*NN + n0_ + r)*CC + h*HD + c4];     \
    }                                                                          \
  }

#define K3V_VWRITE()                                                           \
  {                                                                            \
    _Pragma("unroll")                                                          \
    for (int q = 0; q < 4; ++q) {                                              \
      float x[4] = {gv[q].x, gv[q].y, gv[q].z, gv[q].w};                       \
      xpose4(x, lane);                                                         \
      int nb = 16*q + 4*wid;                                                   \
      s16x4 vh, vl; split4(x, vh, vl);                                         \
      int B = (dV << 7) + (nb << 1);                                           \
      B ^= (dV & 7) << 4;                                                      \
      *(s16x4*)((char*)VtH + B) = vh;                                          \
      *(s16x4*)((char*)VtL + B) = vl;                                          \
    }                                                                          \
  }

// GEMM1: z[l][n] over d, K fragments JIT from global; + klm fold (wave 0)
#define K3V_GEMM1(SUB)                                                         \
  {                                                                            \
    const int n0_ = tile*128 + (SUB)*64;                                       \
    f32x4 zacc[4];                                                             \
    _Pragma("unroll")                                                          \
    for (int t = 0; t < 4; ++t) zacc[t] = (f32x4){0.f, 0.f, 0.f, 0.f};        \
    float4 ksA = make_float4(0.f,0.f,0.f,0.f), ksB = ksA, ksC = ksA, ksD = ksA;\
    _Pragma("unroll")                                                          \
    for (int tn = 0; tn < 4; ++tn) {                                           \
      const float* kp = &K[(size_t)(b*NN + n0_ + tn*16 + lr)*CC + h*HD + lg*8];\
      float4 k00 = *(const float4*)kp;                                         \
      float4 k01 = *(const float4*)(kp + 4);                                   \
      float4 k10 = *(const float4*)(kp + 32);                                  \
      float4 k11 = *(const float4*)(kp + 36);                                  \
      if (wid == 0) { F4ADD(ksA,k00) F4ADD(ksB,k01) F4ADD(ksC,k10) F4ADD(ksD,k11) } \
      float kf[8];                                                             \
      *(float4*)&kf[0] = k00; *(float4*)&kf[4] = k01;                          \
      bf16x8 b0h, b0l; split8(kf, b0h, b0l);                                   \
      *(float4*)&kf[0] = k10; *(float4*)&kf[4] = k11;                          \
      bf16x8 b1h, b1l; split8(kf, b1h, b1l);                                   \
      zacc[tn] = __builtin_amdgcn_mfma_f32_16x16x32_bf16(qh[0], b0h, zacc[tn], 0, 0, 0); \
      zacc[tn] = __builtin_amdgcn_mfma_f32_16x16x32_bf16(qh[0], b0l, zacc[tn], 0, 0, 0); \
      zacc[tn] = __builtin_amdgcn_mfma_f32_16x16x32_bf16(ql[0], b0h, zacc[tn], 0, 0, 0); \
      zacc[tn] = __builtin_amdgcn_mfma_f32_16x16x32_bf16(qh[1], b1h, zacc[tn], 0, 0, 0); \
      zacc[tn] = __builtin_amdgcn_mfma_f32_16x16x32_bf16(qh[1], b1l, zacc[tn], 0, 0, 0); \
      zacc[tn] = __builtin_amdgcn_mfma_f32_16x16x32_bf16(ql[1], b1h, zacc[tn], 0, 0, 0); \
    }                                                                          \
    float e[4][4];                                                             \
    _Pragma("unroll")                                                          \
    for (int tn = 0; tn < 4; ++tn)                                             \
      _Pragma("unroll")                                                        \
      for (int r = 0; r < 4; ++r) e[tn][r] = __expf(zacc[tn][r]);              \
    _Pragma("unroll")                                                          \
    for (int r = 0; r < 4; ++r) {                                              \
      float t = e[0][r] + e[1][r] + e[2][r] + e[3][r];                         \
      srow[r] += shfl_sum16(t);                                                \
    }                                                                          \
    _Pragma("unroll")                                                          \
    for (int tn = 0; tn < 4; ++tn) {                                           \
      const int n = tn*16 + lr;                                                \
      _Pragma("unroll")                                                        \
      for (int r = 0; r < 4; ++r) Erow[(m0 + r)*MATP + n] = e[tn][r];          \
    }                                                                          \
    if (wid == 0) {                                                            \
      RSUM16(ksA) RSUM16(ksB) RSUM16(ksC) RSUM16(ksD)                          \
      if (lr == 0) {                                                           \
        float* kr = klm + (size_t)bh*4096 + (tile*2 + (SUB))*64;               \
        const float s_ = 1.0f/64.0f;                                           \
        *(float4*)(kr + lg*8)          = make_float4(ksA.x*s_, ksA.y*s_, ksA.z*s_, ksA.w*s_); \
        *(float4*)(kr + lg*8 + 4)      = make_float4(ksB.x*s_, ksB.y*s_, ksB.z*s_, ksB.w*s_); \
        *(float4*)(kr + 32 + lg*8)     = make_float4(ksC.x*s_, ksC.y*s_, ksC.z*s_, ksC.w*s_); \
        *(float4*)(kr + 32 + lg*8 + 4) = make_float4(ksD.x*s_, ksD.y*s_, ksD.z*s_, ksD.w*s_); \
      }                                                                        \
    }                                                                          \
  }

#define K3V_GEMM2()                                                            \
  {                                                                            \
    _Pragma("unroll")                                                          \
    for (int ks = 0; ks < 2; ++ks) {                                           \
      float fa[8];                                                             \
      const float* ap = Erow + (wid*16 + lr)*MATP + ks*32 + lg*8;              \
      *(float4*)&fa[0] = *(const float4*)ap;                                   \
      *(float4*)&fa[4] = *(const float4*)(ap + 4);                             \
      bf16x8 ah, al; split8(fa, ah, al);                                       \
      _Pragma("unroll")                                                        \
      for (int tn = 0; tn < 4; ++tn) {                                         \
        bf16x8 bh_ = ldP(VtH, tn*16 + lr, 4*ks + lg);                          \
        bf16x8 bl_ = ldP(VtL, tn*16 + lr, 4*ks + lg);                          \
        acc2[tn] = __builtin_amdgcn_mfma_f32_16x16x32_bf16(ah, bh_, acc2[tn], 0, 0, 0); \
        acc2[tn] = __builtin_amdgcn_mfma_f32_16x16x32_bf16(ah, bl_, acc2[tn], 0, 0, 0); \
        acc2[tn] = __builtin_amdgcn_mfma_f32_16x16x32_bf16(al, bh_, acc2[tn], 0, 0, 0); \
      }                                                                        \
    }                                                                          \
  }

  K3V_VLOAD(0)
  K3V_VWRITE()
  K3V_VLOAD(1)          // next sub's V in flight under GEMM1(0)
  K3V_GEMM1(0)          // no LDS dependency
  __syncthreads();      // Vt(0) visible
  K3V_GEMM2()
  __syncthreads();      // Vt(0) consumed
  K3V_VWRITE()
  K3V_GEMM1(1)
  __syncthreads();      // Vt(1) visible
  K3V_GEMM2()

  if (lr == 0) {
#pragma unroll
    for (int r = 0; r < 4; ++r)
      atomicAdd(&S3[bh*64 + m0 + r], srow[r]);
  }
#pragma unroll
  for (int tn = 0; tn < 4; ++tn)
#pragma unroll
    for (int r = 0; r < 4; ++r)
      atomicAdd(&ACC3[(size_t)bh*4096 + (m0 + r)*64 + tn*16 + lr], acc2[tn][r]);
}

// ---------------- Kernel C: kernel_2 softmax + Newton-Schulz ----------------
// 1024 threads = 16 waves; wave wid -> tile (wr = wid&3, tn = wid>>2).
template<bool FUSE, bool HR, bool HC, bool HG>
__device__ __forceinline__ void mm_mfma(
    const float* __restrict__ Arow, const float* __restrict__ Scol,
    float diagc, float scale,
    float* __restrict__ OutRow, float* __restrict__ OutCol, float* __restrict__ OutGlob,
    int wr, int tn, int lane) {
  const int lr = lane & 15, lg = lane >> 4;
  f32x4 acc = (f32x4){0.f, 0.f, 0.f, 0.f};

#pragma unroll
  for (int ks = 0; ks < 2; ++ks) {
    const int kb = ks*32 + lg*8;
    float fa[8];
    const float* ap = Arow + (wr*16 + lr)*MATP + kb;
    *(float4*)&fa[0] = *(const float4*)ap;
    *(float4*)&fa[4] = *(const float4*)(ap + 4);
    bf16x8 ah, al; split8(fa, ah, al);
    float fb[8];
    const float* bp = Scol + (tn*16 + lr)*MATP + kb;
    *(float4*)&fb[0] = *(const float4*)bp;
    *(float4*)&fb[4] = *(const float4*)(bp + 4);
    if (FUSE) {
      int diff = (tn*16 + lr) - kb;
#pragma unroll
      for (int i = 0; i < 8; ++i) fb[i] = (i == diff ? diagc : 0.f) - fb[i];
    }
    bf16x8 bh_, bl_; split8(fb, bh_, bl_);
    acc = __builtin_amdgcn_mfma_f32_16x16x32_bf16(ah, bh_, acc, 0, 0, 0);
    acc = __builtin_amdgcn_mfma_f32_16x16x32_bf16(ah, bl_, acc, 0, 0, 0);
    acc = __builtin_amdgcn_mfma_f32_16x16x32_bf16(al, bh_, acc, 0, 0, 0);
  }
  __syncthreads();
  const int n = tn*16 + lr, m0 = wr*16 + lg*4;
  float v0 = scale*acc[0], v1 = scale*acc[1], v2 = scale*acc[2], v3 = scale*acc[3];
  if (HC) *(float4*)&OutCol[n*MATP + m0] = make_float4(v0, v1, v2, v3);
  if (HR) {
    OutRow[(m0+0)*MATP + n] = v0;
    OutRow[(m0+1)*MATP + n] = v1;
    OutRow[(m0+2)*MATP + n] = v2;
    OutRow[(m0+3)*MATP + n] = v3;
  }
  if (HG) {
    OutGlob[(m0+0)*64 + n] = v0;
    OutGlob[(m0+1)*64 + n] = v1;
    OutGlob[(m0+2)*64 + n] = v2;
    OutGlob[(m0+3)*64 + n] = v3;
  }
  __syncthreads();
}

__global__ __launch_bounds__(1024, 1) void inv_kernel(
    const float* __restrict__ qlm, const float* __restrict__ klm,
    const float* __restrict__ S3, const float* __restrict__ ACC3,
    float* __restrict__ W) {
  extern __shared__ float sm[];
  float* K2row = sm;
  float* Vmrow = sm + 1*MATE;
  float* Vmcol = sm + 2*MATE;
  float* Xrow  = sm + 3*MATE;
  float* Xcol  = sm + 4*MATE;
  float* Ycol  = sm + 5*MATE;
  float* Zcol  = sm + 6*MATE;
  float* rs    = sm + 7*MATE;        // 64 x 4 partials
  float* rinv  = rs + 256;           // 64
  float* red   = rinv + 64;          // 1
  const int bh = blockIdx.x, tid = threadIdx.x;
  const int wid = tid >> 6, lane = tid & 63;
  const int wr = wid & 3, tn = wid >> 2;
  const int lr = lane & 15, lg = lane >> 4;
  const int m0 = wr*16 + lg*4, n = tn*16 + lr;

  {
    int f = tid, r = f >> 4, c4 = (f & 15) << 2;
    *(float4*)&Xrow[r*MATP + c4] = *(const float4*)&qlm[(size_t)bh*4096 + f*4];
    *(float4*)&Xcol[r*MATP + c4] = *(const float4*)&klm[(size_t)bh*4096 + f*4];
  }
  __syncthreads();

  {
    f32x4 zacc = (f32x4){0.f, 0.f, 0.f, 0.f};
#pragma unroll
    for (int ks = 0; ks < 2; ++ks) {
      const int kb = ks*32 + lg*8;
      float fa[8];
      const float* ap = Xrow + (wr*16 + lr)*MATP + kb;
      *(float4*)&fa[0] = *(const float4*)ap;
      *(float4*)&fa[4] = *(const float4*)(ap + 4);
      bf16x8 ah, al; split8(fa, ah, al);
      float fb[8];
      const float* bp = Xcol + (tn*16 + lr)*MATP + kb;
      *(float4*)&fb[0] = *(const float4*)bp;
      *(float4*)&fb[4] = *(const float4*)(bp + 4);
      bf16x8 bh_, bl_; split8(fb, bh_, bl_);
      zacc = __builtin_amdgcn_mfma_f32_16x16x32_bf16(ah, bh_, zacc, 0, 0, 0);
      zacc = __builtin_amdgcn_mfma_f32_16x16x32_bf16(ah, bl_, zacc, 0, 0, 0);
      zacc = __builtin_amdgcn_mfma_f32_16x16x32_bf16(al, bh_, zacc, 0, 0, 0);
    }
    float e[4];
#pragma unroll
    for (int r = 0; r < 4; ++r) e[r] = __expf(zacc[r]);
    float part[4];
#pragma unroll
    for (int r = 0; r < 4; ++r) part[r] = shfl_sum16(e[r]);
    if (lr == 0) {
#pragma unroll
      for (int r = 0; r < 4; ++r) rs[(m0 + r)*4 + tn] = part[r];
    }
    __syncthreads();
    if (tid < 64)
      rinv[tid] = 1.0f / (rs[tid*4] + rs[tid*4+1] + rs[tid*4+2] + rs[tid*4+3]);
    __syncthreads();
#pragma unroll
    for (int r = 0; r < 4; ++r)
      K2row[(m0+r)*MATP + n] = e[r] * rinv[m0 + r];
  }
  __syncthreads();

  if (tid < 64) {
    float c = 0.f;
#pragma unroll 8
    for (int i = 0; i < 64; ++i) c += K2row[i*MATP + tid];
#pragma unroll
    for (int m = 1; m < 64; m <<= 1) c = fmaxf(c, __shfl_xor(c, m, 64));
    if (tid == 0) red[0] = 1.0f / c;
  }
  __syncthreads();
  const float invden = red[0];

  {
    int f = tid, i = f >> 4, c4 = (f & 15) << 2;
    float4 kv = *(const float4*)&K2row[i*MATP + c4];
    kv.x *= invden; kv.y *= invden; kv.z *= invden; kv.w *= invden;
    *(float4*)&Vmcol[i*MATP + c4] = kv;
    Vmrow[(c4+0)*MATP + i] = kv.x;
    Vmrow[(c4+1)*MATP + i] = kv.y;
    Vmrow[(c4+2)*MATP + i] = kv.z;
    Vmrow[(c4+3)*MATP + i] = kv.w;
  }
  __syncthreads();

  for (int it = 0; it < 6; ++it) {
    mm_mfma<false, true,  true,  false>(K2row, Vmcol, 0.f,  1.0f,  Xrow, Xcol, nullptr, wr, tn, lane);
    mm_mfma<true,  false, true,  false>(Xrow,  Xcol,  7.f,  1.0f,  nullptr, Ycol, nullptr, wr, tn, lane);
    mm_mfma<true,  false, true,  false>(Xrow,  Ycol,  15.f, 1.0f,  nullptr, Zcol, nullptr, wr, tn, lane);
    mm_mfma<true,  true,  true,  false>(Vmrow, Zcol,  13.f, 0.25f, Vmrow, Vmcol, nullptr, wr, tn, lane);
  }

  {
    int f = tid, k = f >> 4, c4 = (f & 15) << 2;
    float4 tv = *(const float4*)&ACC3[(size_t)bh*4096 + f*4];
    float ri = 1.0f / S3[bh*64 + k];
    Ycol[(c4+0)*MATP + k] = tv.x * ri;
    Ycol[(c4+1)*MATP + k] = tv.y * ri;
    Ycol[(c4+2)*MATP + k] = tv.z * ri;
    Ycol[(c4+3)*MATP + k] = tv.w * ri;
  }
  __syncthreads();
  mm_mfma<false, false, false, true>(Vmrow, Ycol, 0.f, 1.0f, nullptr, nullptr, W + (size_t)bh*4096, wr, tn, lane);
}

// ---------------- Kernel D: out = softmax(q k_lm^T) @ W ----------------
// klm JIT from global (L2-resident per head); single barrier.
__global__ __launch_bounds__(256, 4) void out_kernel(
    const float* __restrict__ Q, const float* __restrict__ klm,
    const float* __restrict__ W, float* __restrict__ Out) {
  __shared__ alignas(16) short WtH[64*64], WtL[64*64];  // W^T planes (16 KB)
  __shared__ alignas(16) float Prow[64*MATP];           // P fp32 (17.4 KB)
  const int bh = blockIdx.y, b = bh >> 4, h = bh & 15;
  const int n0 = blockIdx.x * 64;
  const int tid = threadIdx.x;
  const int wid = tid >> 6, lane = tid & 63;
  const int lr = lane & 15, lg = lane >> 4;
  const int m0 = wid*16 + lg*4;

  // stage W^T planes via in-wave transpose
  const int dW = 4*lr + lg;
#pragma unroll
  for (int q = 0; q < 4; ++q) {
    int f = tid + 256*q;
    int r = f >> 4, c4 = (f & 15) << 2;
    float4 wv = *(const float4*)&W[(size_t)bh*4096 + r*64 + c4];
    float x[4] = {wv.x, wv.y, wv.z, wv.w};
    xpose4(x, lane);
    int nb = 16*q + 4*wid;
    s16x4 wh, wl; split4(x, wh, wl);
    int B = (dW << 7) + (nb << 1);
    B ^= (dW & 7) << 4;
    *(s16x4*)((char*)WtH + B) = wh;
    *(s16x4*)((char*)WtL + B) = wl;
  }

  // Q A-fragments -> registers (scaled, split once)
  bf16x8 qh[2], qlo[2];
#pragma unroll
  for (int ks = 0; ks < 2; ++ks) {
    const float* qp = Q + ((size_t)b*NN + n0 + wid*16 + lr)*CC + h*HD + ks*32 + lg*8;
    float qf[8];
    *(float4*)&qf[0] = *(const float4*)qp;
    *(float4*)&qf[4] = *(const float4*)(qp + 4);
#pragma unroll
    for (int i = 0; i < 8; ++i) qf[i] *= 0.125f;
    split8(qf, qh[ks], qlo[ks]);
  }

  // GEMM1: z[n][l] = sum_d Q[n][d] * klm[l][d]  (klm JIT from global)
  f32x4 zacc[4];
#pragma unroll
  for (int t = 0; t < 4; ++t) zacc[t] = (f32x4){0.f, 0.f, 0.f, 0.f};
#pragma unroll
  for (int tn = 0; tn < 4; ++tn) {
    const float* kp = &klm[(size_t)bh*4096 + (tn*16 + lr)*64 + lg*8];
    float4 k00 = *(const float4*)kp;
    float4 k01 = *(const float4*)(kp + 4);
    float4 k10 = *(const float4*)(kp + 32);
    float4 k11 = *(const float4*)(kp + 36);
    float kf[8];
    *(float4*)&kf[0] = k00; *(float4*)&kf[4] = k01;
    bf16x8 b0h, b0l; split8(kf, b0h, b0l);
    *(float4*)&kf[0] = k10; *(float4*)&kf[4] = k11;
    bf16x8 b1h, b1l; split8(kf, b1h, b1l);
    zacc[tn] = __builtin_amdgcn_mfma_f32_16x16x32_bf16(qh[0], b0h, zacc[tn], 0, 0, 0);
    zacc[tn] = __builtin_amdgcn_mfma_f32_16x16x32_bf16(qh[0], b0l, zacc[tn], 0, 0, 0);
    zacc[tn] = __builtin_amdgcn_mfma_f32_16x16x32_bf16(qlo[0], b0h, zacc[tn], 0, 0, 0);
    zacc[tn] = __builtin_amdgcn_mfma_f32_16x16x32_bf16(qh[1], b1h, zacc[tn], 0, 0, 0);
    zacc[tn] = __builtin_amdgcn_mfma_f32_16x16x32_bf16(qh[1], b1l, zacc[tn], 0, 0, 0);
    zacc[tn] = __builtin_amdgcn_mfma_f32_16x16x32_bf16(qlo[1], b1h, zacc[tn], 0, 0, 0);
  }
  // softmax rows -> own rows of Prow
  float e[4][4];
#pragma unroll
  for (int tn = 0; tn < 4; ++tn)
#pragma unroll
    for (int r = 0; r < 4; ++r) e[tn][r] = __expf(zacc[tn][r]);
#pragma unroll
  for (int r = 0; r < 4; ++r) {
    float t = e[0][r] + e[1][r] + e[2][r] + e[3][r];
    t = shfl_sum16(t);
    float ri = 1.0f / t;
#pragma unroll
    for (int tn = 0; tn < 4; ++tn) e[tn][r] *= ri;
  }
#pragma unroll
  for (int tn = 0; tn < 4; ++tn) {
    const int n = tn*16 + lr;
#pragma unroll
    for (int r = 0; r < 4; ++r) Prow[(m0+r)*MATP + n] = e[tn][r];
  }
  __syncthreads();   // Wt visible

  // GEMM2: o[n][d] = sum_l P[n][l] * W[l][d]
  f32x4 oacc[4];
#pragma unroll
  for (int t = 0; t < 4; ++t) oacc[t] = (f32x4){0.f, 0.f, 0.f, 0.f};
#pragma unroll
  for (int ks = 0; ks < 2; ++ks) {
    float fa[8];
    const float* ap = Prow + (wid*16 + lr)*MATP + ks*32 + lg*8;
    *(float4*)&fa[0] = *(const float4*)ap;
    *(float4*)&fa[4] = *(const float4*)(ap + 4);
    bf16x8 ah, al; split8(fa, ah, al);
#pragma unroll
    for (int tn = 0; tn < 4; ++tn) {
      bf16x8 bh_ = ldP(WtH, tn*16 + lr, 4*ks + lg);
      bf16x8 bl_ = ldP(WtL, tn*16 + lr, 4*ks + lg);
      oacc[tn] = __builtin_amdgcn_mfma_f32_16x16x32_bf16(ah, bh_, oacc[tn], 0, 0, 0);
      oacc[tn] = __builtin_amdgcn_mfma_f32_16x16x32_bf16(ah, bl_, oacc[tn], 0, 0, 0);
      oacc[tn] = __builtin_amdgcn_mfma_f32_16x16x32_bf16(al, bh_, oacc[tn], 0, 0, 0);
    }
  }
#pragma unroll
  for (int tn = 0; tn < 4; ++tn) {
    const int d = tn*16 + lr;
#pragma unroll
    for (int r = 0; r < 4; ++r)
      Out[((size_t)b*NN + n0 + m0 + r)*CC + h*HD + d] = oacc[tn][r];
  }
}

// ---------------- host ----------------
extern "C" void kernel_launch(void* const* d_in, const int* in_sizes, int n_in,
                              void* d_out, int out_size, void* d_ws, size_t ws_size,
                              hipStream_t stream) {
  const float* Q = (const float*)d_in[0];
  const float* K = (const float*)d_in[1];
  const float* V = (const float*)d_in[2];
  float* out = (float*)d_out;
  float* ws  = (float*)d_ws;

  float* qlm  = ws;               // 262144
  float* klm  = ws + 262144;      // 262144
  float* S3   = ws + 524288;      // 4096
  float* ACC3 = ws + 528384;      // 262144
  float* Wm   = ws + 790528;      // 262144

  size_t shC = (size_t)(7*MATE + 384)*sizeof(float);   // ~123 KB
  hipFuncSetAttribute((const void*)inv_kernel,
                      hipFuncAttributeMaxDynamicSharedMemorySize, (int)shC);

  hipMemsetAsync(S3, 0, (4096 + 262144)*sizeof(float), stream);

  lm_q_kernel<<<dim3(16, BHN), 256, 0, stream>>>(Q, qlm);
  k3v_kernel <<<dim3(32, BHN), 256, 0, stream>>>(K, V, qlm, klm, S3, ACC3);
  inv_kernel <<<dim3(BHN),    1024, shC, stream>>>(qlm, klm, S3, ACC3, Wm);
  out_kernel <<<dim3(64, BHN), 256, 0, stream>>>(Q, klm, Wm, out);
}

// Round 9
// 150.507 us; speedup vs baseline: 1.0606x; 1.0606x over previous
//
#include <hip/hip_runtime.h>
#include <math.h>

#define BB 4
#define NN 4096
#define CC 1024
#define HH 16
#define HD 64
#define LM 64
#define SEG 64
#define BHN (BB*HH)          // 64
#define MATP 68              // fp32 row stride (inv buffers + Erow/Prow)
#define MATE (64*MATP)
#define NTILE 32             // k3v grid.x
#define APROW 4160           // 4096 acc + 64 srow per (tile,bh)

typedef __attribute__((ext_vector_type(8))) short bf16x8;
typedef __attribute__((ext_vector_type(4))) short s16x4;
typedef __attribute__((ext_vector_type(4))) float f32x4;

__device__ __forceinline__ float shfl_sum16(float v) {
  v += __shfl_xor(v, 1, 16);
  v += __shfl_xor(v, 2, 16);
  v += __shfl_xor(v, 4, 16);
  v += __shfl_xor(v, 8, 16);
  return v;
}

// split fp32 -> bf16 hi (chop) + bf16 lo (chop of residual); rel err ~2^-16
__device__ __forceinline__ void split8(const float* f, bf16x8& hi, bf16x8& lo) {
#pragma unroll
  for (int i = 0; i < 8; ++i) {
    unsigned u = __builtin_bit_cast(unsigned, f[i]);
    float hf = __builtin_bit_cast(float, u & 0xFFFF0000u);
    hi[i] = (short)(u >> 16);
    float l = f[i] - hf;
    unsigned ul = __builtin_bit_cast(unsigned, l);
    lo[i] = (short)(ul >> 16);
  }
}

__device__ __forceinline__ void split4(const float* f, s16x4& hi, s16x4& lo) {
#pragma unroll
  for (int i = 0; i < 4; ++i) {
    unsigned u = __builtin_bit_cast(unsigned, f[i]);
    float hf = __builtin_bit_cast(float, u & 0xFFFF0000u);
    hi[i] = (short)(u >> 16);
    float l = f[i] - hf;
    unsigned ul = __builtin_bit_cast(unsigned, l);
    lo[i] = (short)(ul >> 16);
  }
}

// m214-style plane: 64 rows x 64 shorts (128B rows), byte ^= (row&7)<<4.
__device__ __forceinline__ int planeAddr(int row, int cd) {
  int B = (row << 7) + (cd << 4);
  return B ^ ((row & 7) << 4);
}
__device__ __forceinline__ bf16x8 ldP(const short* __restrict__ P, int row, int cd) {
  return *(const bf16x8*)((const char*)P + planeAddr(row, cd));
}

// in-wave 4x4 transpose among lanes {l, l^16, l^32, l^48}
__device__ __forceinline__ void xpose4(float x[4], int lane) {
  bool p1 = (lane >> 4) & 1;
  float s0 = p1 ? x[0] : x[1], s1 = p1 ? x[2] : x[3];
  float r0 = __shfl_xor(s0, 16, 64), r1 = __shfl_xor(s1, 16, 64);
  if (p1) { x[0] = r0; x[2] = r1; } else { x[1] = r0; x[3] = r1; }
  bool p2 = (lane >> 5) & 1;
  s0 = p2 ? x[0] : x[2]; s1 = p2 ? x[1] : x[3];
  r0 = __shfl_xor(s0, 32, 64); r1 = __shfl_xor(s1, 32, 64);
  if (p2) { x[0] = r0; x[1] = r1; } else { x[2] = r0; x[3] = r1; }
}

// ---------------- Kernel A: landmark means (Q and K) ----------------
__global__ __launch_bounds__(256) void lm_kernel(
    const float* __restrict__ Q, const float* __restrict__ K,
    float* __restrict__ qlm, float* __restrict__ klm) {
  int bh = blockIdx.y; int b = bh >> 4; int h = bh & 15;
  int tid = threadIdx.x;
  int l = blockIdx.x * 4 + (tid >> 6);
  int d = tid & 63;
  const float* qbase = Q + ((size_t)b*NN + (size_t)l*SEG)*CC + h*HD + d;
  const float* kbase = K + ((size_t)b*NN + (size_t)l*SEG)*CC + h*HD + d;
  float sq = 0.f, sk = 0.f;
#pragma unroll 8
  for (int s = 0; s < SEG; ++s) {
    sq += qbase[(size_t)s*CC];
    sk += kbase[(size_t)s*CC];
  }
  qlm[(size_t)bh*4096 + l*64 + d] = sq * (1.0f/(64.0f*8.0f));
  klm[(size_t)bh*4096 + l*64 + d] = sk * (1.0f/64.0f);
}

// ---------------- Kernel B: partials of kernel_3 @ V (R7 structure, no atomics) ----------------
__global__ __launch_bounds__(256, 3) void k3v_kernel(
    const float* __restrict__ K, const float* __restrict__ V,
    const float* __restrict__ qlm, float* __restrict__ ACC3p) {
  __shared__ alignas(16) short KEh[64*64], KEl[64*64];  // K tile [n][d] planes
  __shared__ alignas(16) short VtH[64*64], VtL[64*64];  // V^T [d][n] planes
  __shared__ alignas(16) float Erow[64*MATP];           // E fp32 [l][n]
  const int bh = blockIdx.y, b = bh >> 4, h = bh & 15;
  const int tile = blockIdx.x, tid = threadIdx.x;
  const int wid = tid >> 6, lane = tid & 63;
  const int lr = lane & 15, lg = lane >> 4;
  const int m0 = wid*16 + lg*4;

  bf16x8 qh[2], ql[2];
#pragma unroll
  for (int ks = 0; ks < 2; ++ks) {
    const float* qp = qlm + (size_t)bh*4096 + (wid*16 + lr)*64 + ks*32 + lg*8;
    float qf[8];
    *(float4*)&qf[0] = *(const float4*)qp;
    *(float4*)&qf[4] = *(const float4*)(qp + 4);
    split8(qf, qh[ks], ql[ks]);
  }

  f32x4 acc2[4];
#pragma unroll
  for (int t = 0; t < 4; ++t) acc2[t] = (f32x4){0.f, 0.f, 0.f, 0.f};
  float srow[4] = {0.f, 0.f, 0.f, 0.f};

  const int rk0 = tid >> 3,        ck = tid & 7;
  const int rk1 = (tid + 256) >> 3;
  const int dV  = 4*lr + lg;

  float4 gk[2][2], gv[4];

#define K3V_LOAD(SUB)                                                          \
  {                                                                            \
    const int n0_ = tile*128 + (SUB)*64;                                       \
    const float* kb0 = &K[((size_t)b*NN + n0_ + rk0)*CC + h*HD + ck*8];        \
    const float* kb1 = &K[((size_t)b*NN + n0_ + rk1)*CC + h*HD + ck*8];        \
    gk[0][0] = *(const float4*)kb0;  gk[0][1] = *(const float4*)(kb0 + 4);     \
    gk[1][0] = *(const float4*)kb1;  gk[1][1] = *(const float4*)(kb1 + 4);     \
    _Pragma("unroll")                                                          \
    for (int q = 0; q < 4; ++q) {                                              \
      int f = tid + 256*q;                                                     \
      int r = f >> 4, c4 = (f & 15) << 2;                                      \
      gv[q] = *(const float4*)&V[((size_t)b*NN + n0_ + r)*CC + h*HD + c4];     \
    }                                                                          \
  }

#define K3V_WRITE()                                                            \
  {                                                                            \
    _Pragma("unroll")                                                          \
    for (int q2 = 0; q2 < 2; ++q2) {                                           \
      float kf[8];                                                             \
      *(float4*)&kf[0] = gk[q2][0];                                            \
      *(float4*)&kf[4] = gk[q2][1];                                            \
      bf16x8 khv, klv; split8(kf, khv, klv);                                   \
      int r = q2 ? rk1 : rk0;                                                  \
      int A = planeAddr(r, ck);                                                \
      *(bf16x8*)((char*)KEh + A) = khv;                                        \
      *(bf16x8*)((char*)KEl + A) = klv;                                        \
    }                                                                          \
    _Pragma("unroll")                                                          \
    for (int q = 0; q < 4; ++q) {                                              \
      float x[4] = {gv[q].x, gv[q].y, gv[q].z, gv[q].w};                       \
      xpose4(x, lane);                                                         \
      int nb = 16*q + 4*wid;                                                   \
      s16x4 vh, vl; split4(x, vh, vl);                                         \
      int B = (dV << 7) + (nb << 1);                                           \
      B ^= (dV & 7) << 4;                                                      \
      *(s16x4*)((char*)VtH + B) = vh;                                          \
      *(s16x4*)((char*)VtL + B) = vl;                                          \
    }                                                                          \
  }

#define K3V_COMPUTE()                                                          \
  {                                                                            \
    f32x4 zacc[4];                                                             \
    _Pragma("unroll")                                                          \
    for (int t = 0; t < 4; ++t) zacc[t] = (f32x4){0.f, 0.f, 0.f, 0.f};        \
    _Pragma("unroll")                                                          \
    for (int ks = 0; ks < 2; ++ks) {                                           \
      _Pragma("unroll")                                                        \
      for (int tn = 0; tn < 4; ++tn) {                                         \
        bf16x8 bh_ = ldP(KEh, tn*16 + lr, 4*ks + lg);                          \
        bf16x8 bl_ = ldP(KEl, tn*16 + lr, 4*ks + lg);                          \
        zacc[tn] = __builtin_amdgcn_mfma_f32_16x16x32_bf16(qh[ks], bh_, zacc[tn], 0, 0, 0); \
        zacc[tn] = __builtin_amdgcn_mfma_f32_16x16x32_bf16(qh[ks], bl_, zacc[tn], 0, 0, 0); \
        zacc[tn] = __builtin_amdgcn_mfma_f32_16x16x32_bf16(ql[ks], bh_, zacc[tn], 0, 0, 0); \
      }                                                                        \
    }                                                                          \
    float e[4][4];                                                             \
    _Pragma("unroll")                                                          \
    for (int tn = 0; tn < 4; ++tn)                                             \
      _Pragma("unroll")                                                        \
      for (int r = 0; r < 4; ++r) e[tn][r] = __expf(zacc[tn][r]);              \
    _Pragma("unroll")                                                          \
    for (int r = 0; r < 4; ++r) {                                              \
      float t = e[0][r] + e[1][r] + e[2][r] + e[3][r];                         \
      srow[r] += shfl_sum16(t);                                                \
    }                                                                          \
    _Pragma("unroll")                                                          \
    for (int tn = 0; tn < 4; ++tn) {                                           \
      const int n = tn*16 + lr;                                                \
      _Pragma("unroll")                                                        \
      for (int r = 0; r < 4; ++r) Erow[(m0 + r)*MATP + n] = e[tn][r];          \
    }                                                                          \
    _Pragma("unroll")                                                          \
    for (int ks = 0; ks < 2; ++ks) {                                           \
      float fa[8];                                                             \
      const float* ap = Erow + (wid*16 + lr)*MATP + ks*32 + lg*8;              \
      *(float4*)&fa[0] = *(const float4*)ap;                                   \
      *(float4*)&fa[4] = *(const float4*)(ap + 4);                             \
      bf16x8 ah, al; split8(fa, ah, al);                                       \
      _Pragma("unroll")                                                        \
      for (int tn = 0; tn < 4; ++tn) {                                         \
        bf16x8 bh_ = ldP(VtH, tn*16 + lr, 4*ks + lg);                          \
        bf16x8 bl_ = ldP(VtL, tn*16 + lr, 4*ks + lg);                          \
        acc2[tn] = __builtin_amdgcn_mfma_f32_16x16x32_bf16(ah, bh_, acc2[tn], 0, 0, 0); \
        acc2[tn] = __builtin_amdgcn_mfma_f32_16x16x32_bf16(ah, bl_, acc2[tn], 0, 0, 0); \
        acc2[tn] = __builtin_amdgcn_mfma_f32_16x16x32_bf16(al, bh_, acc2[tn], 0, 0, 0); \
      }                                                                        \
    }                                                                          \
  }

  K3V_LOAD(0)
  K3V_WRITE()
  __syncthreads();
  K3V_LOAD(1)
  K3V_COMPUTE()
  __syncthreads();
  K3V_WRITE()
  __syncthreads();
  K3V_COMPUTE()

  // private per-tile stores (no atomics); reduce_kernel sums over tiles
  float* accp = ACC3p + ((size_t)tile*BHN + bh)*APROW;
  if (lr == 0) {
#pragma unroll
    for (int r = 0; r < 4; ++r) accp[4096 + m0 + r] = srow[r];
  }
#pragma unroll
  for (int tn = 0; tn < 4; ++tn)
#pragma unroll
    for (int r = 0; r < 4; ++r)
      accp[(m0 + r)*64 + tn*16 + lr] = acc2[tn][r];
}

// ---------------- Kernel B2: reduce partials -> ACC3, S3 ----------------
__global__ __launch_bounds__(256) void reduce_kernel(
    const float* __restrict__ ACC3p, float* __restrict__ ACC3, float* __restrict__ S3) {
  const int bh = blockIdx.y;
  const int f4 = blockIdx.x*256 + threadIdx.x;   // float4 index, 1040 per bh
  if (f4 >= APROW/4) return;
  float4 s = make_float4(0.f, 0.f, 0.f, 0.f);
  const float* base = ACC3p + (size_t)bh*APROW + f4*4;
#pragma unroll 4
  for (int t = 0; t < NTILE; ++t) {
    float4 v = *(const float4*)(base + (size_t)t*BHN*APROW);
    s.x += v.x; s.y += v.y; s.z += v.z; s.w += v.w;
  }
  const int f = f4*4;
  if (f < 4096) *(float4*)&ACC3[(size_t)bh*4096 + f] = s;
  else          *(float4*)&S3[bh*64 + (f - 4096)] = s;
}

// ---------------- Kernel C: kernel_2 softmax + Newton-Schulz (16 waves) ----------------
template<bool FUSE, bool HR, bool HC, bool HG>
__device__ __forceinline__ void mm_mfma(
    const float* __restrict__ Arow, const float* __restrict__ Scol,
    float diagc, float scale,
    float* __restrict__ OutRow, float* __restrict__ OutCol, float* __restrict__ OutGlob,
    int wr, int tn, int lane) {
  const int lr = lane & 15, lg = lane >> 4;
  f32x4 acc = (f32x4){0.f, 0.f, 0.f, 0.f};

#pragma unroll
  for (int ks = 0; ks < 2; ++ks) {
    const int kb = ks*32 + lg*8;
    float fa[8];
    const float* ap = Arow + (wr*16 + lr)*MATP + kb;
    *(float4*)&fa[0] = *(const float4*)ap;
    *(float4*)&fa[4] = *(const float4*)(ap + 4);
    bf16x8 ah, al; split8(fa, ah, al);
    float fb[8];
    const float* bp = Scol + (tn*16 + lr)*MATP + kb;
    *(float4*)&fb[0] = *(const float4*)bp;
    *(float4*)&fb[4] = *(const float4*)(bp + 4);
    if (FUSE) {
      int diff = (tn*16 + lr) - kb;
#pragma unroll
      for (int i = 0; i < 8; ++i) fb[i] = (i == diff ? diagc : 0.f) - fb[i];
    }
    bf16x8 bh_, bl_; split8(fb, bh_, bl_);
    acc = __builtin_amdgcn_mfma_f32_16x16x32_bf16(ah, bh_, acc, 0, 0, 0);
    acc = __builtin_amdgcn_mfma_f32_16x16x32_bf16(ah, bl_, acc, 0, 0, 0);
    acc = __builtin_amdgcn_mfma_f32_16x16x32_bf16(al, bh_, acc, 0, 0, 0);
  }
  __syncthreads();
  const int n = tn*16 + lr, m0 = wr*16 + lg*4;
  float v0 = scale*acc[0], v1 = scale*acc[1], v2 = scale*acc[2], v3 = scale*acc[3];
  if (HC) *(float4*)&OutCol[n*MATP + m0] = make_float4(v0, v1, v2, v3);
  if (HR) {
    OutRow[(m0+0)*MATP + n] = v0;
    OutRow[(m0+1)*MATP + n] = v1;
    OutRow[(m0+2)*MATP + n] = v2;
    OutRow[(m0+3)*MATP + n] = v3;
  }
  if (HG) {
    OutGlob[(m0+0)*64 + n] = v0;
    OutGlob[(m0+1)*64 + n] = v1;
    OutGlob[(m0+2)*64 + n] = v2;
    OutGlob[(m0+3)*64 + n] = v3;
  }
  __syncthreads();
}

__global__ __launch_bounds__(1024, 1) void inv_kernel(
    const float* __restrict__ qlm, const float* __restrict__ klm,
    const float* __restrict__ S3, const float* __restrict__ ACC3,
    float* __restrict__ W) {
  extern __shared__ float sm[];
  float* K2row = sm;
  float* Vmrow = sm + 1*MATE;
  float* Vmcol = sm + 2*MATE;
  float* Xrow  = sm + 3*MATE;
  float* Xcol  = sm + 4*MATE;
  float* Ycol  = sm + 5*MATE;
  float* Zcol  = sm + 6*MATE;
  float* rs    = sm + 7*MATE;        // 64 x 4 partials
  float* rinv  = rs + 256;           // 64
  float* red   = rinv + 64;          // 1
  const int bh = blockIdx.x, tid = threadIdx.x;
  const int wid = tid >> 6, lane = tid & 63;
  const int wr = wid & 3, tn = wid >> 2;
  const int lr = lane & 15, lg = lane >> 4;
  const int m0 = wr*16 + lg*4, n = tn*16 + lr;

  {
    int f = tid, r = f >> 4, c4 = (f & 15) << 2;
    *(float4*)&Xrow[r*MATP + c4] = *(const float4*)&qlm[(size_t)bh*4096 + f*4];
    *(float4*)&Xcol[r*MATP + c4] = *(const float4*)&klm[(size_t)bh*4096 + f*4];
  }
  __syncthreads();

  {
    f32x4 zacc = (f32x4){0.f, 0.f, 0.f, 0.f};
#pragma unroll
    for (int ks = 0; ks < 2; ++ks) {
      const int kb = ks*32 + lg*8;
      float fa[8];
      const float* ap = Xrow + (wr*16 + lr)*MATP + kb;
      *(float4*)&fa[0] = *(const float4*)ap;
      *(float4*)&fa[4] = *(const float4*)(ap + 4);
      bf16x8 ah, al; split8(fa, ah, al);
      float fb[8];
      const float* bp = Xcol + (tn*16 + lr)*MATP + kb;
      *(float4*)&fb[0] = *(const float4*)bp;
      *(float4*)&fb[4] = *(const float4*)(bp + 4);
      bf16x8 bh_, bl_; split8(fb, bh_, bl_);
      zacc = __builtin_amdgcn_mfma_f32_16x16x32_bf16(ah, bh_, zacc, 0, 0, 0);
      zacc = __builtin_amdgcn_mfma_f32_16x16x32_bf16(ah, bl_, zacc, 0, 0, 0);
      zacc = __builtin_amdgcn_mfma_f32_16x16x32_bf16(al, bh_, zacc, 0, 0, 0);
    }
    float e[4];
#pragma unroll
    for (int r = 0; r < 4; ++r) e[r] = __expf(zacc[r]);
    float part[4];
#pragma unroll
    for (int r = 0; r < 4; ++r) part[r] = shfl_sum16(e[r]);
    if (lr == 0) {
#pragma unroll
      for (int r = 0; r < 4; ++r) rs[(m0 + r)*4 + tn] = part[r];
    }
    __syncthreads();
    if (tid < 64)
      rinv[tid] = 1.0f / (rs[tid*4] + rs[tid*4+1] + rs[tid*4+2] + rs[tid*4+3]);
    __syncthreads();
#pragma unroll
    for (int r = 0; r < 4; ++r)
      K2row[(m0+r)*MATP + n] = e[r] * rinv[m0 + r];
  }
  __syncthreads();

  if (tid < 64) {
    float c = 0.f;
#pragma unroll 8
    for (int i = 0; i < 64; ++i) c += K2row[i*MATP + tid];
#pragma unroll
    for (int m = 1; m < 64; m <<= 1) c = fmaxf(c, __shfl_xor(c, m, 64));
    if (tid == 0) red[0] = 1.0f / c;
  }
  __syncthreads();
  const float invden = red[0];

  {
    int f = tid, i = f >> 4, c4 = (f & 15) << 2;
    float4 kv = *(const float4*)&K2row[i*MATP + c4];
    kv.x *= invden; kv.y *= invden; kv.z *= invden; kv.w *= invden;
    *(float4*)&Vmcol[i*MATP + c4] = kv;
    Vmrow[(c4+0)*MATP + i] = kv.x;
    Vmrow[(c4+1)*MATP + i] = kv.y;
    Vmrow[(c4+2)*MATP + i] = kv.z;
    Vmrow[(c4+3)*MATP + i] = kv.w;
  }
  __syncthreads();

  for (int it = 0; it < 6; ++it) {
    mm_mfma<false, true,  true,  false>(K2row, Vmcol, 0.f,  1.0f,  Xrow, Xcol, nullptr, wr, tn, lane);
    mm_mfma<true,  false, true,  false>(Xrow,  Xcol,  7.f,  1.0f,  nullptr, Ycol, nullptr, wr, tn, lane);
    mm_mfma<true,  false, true,  false>(Xrow,  Ycol,  15.f, 1.0f,  nullptr, Zcol, nullptr, wr, tn, lane);
    mm_mfma<true,  true,  true,  false>(Vmrow, Zcol,  13.f, 0.25f, Vmrow, Vmcol, nullptr, wr, tn, lane);
  }

  {
    int f = tid, k = f >> 4, c4 = (f & 15) << 2;
    float4 tv = *(const float4*)&ACC3[(size_t)bh*4096 + f*4];
    float ri = 1.0f / S3[bh*64 + k];
    Ycol[(c4+0)*MATP + k] = tv.x * ri;
    Ycol[(c4+1)*MATP + k] = tv.y * ri;
    Ycol[(c4+2)*MATP + k] = tv.z * ri;
    Ycol[(c4+3)*MATP + k] = tv.w * ri;
  }
  __syncthreads();
  mm_mfma<false, false, false, true>(Vmrow, Ycol, 0.f, 1.0f, nullptr, nullptr, W + (size_t)bh*4096, wr, tn, lane);
}

// ---------------- Kernel D: out = softmax(q k_lm^T) @ W (klm JIT, 4/CU) ----------------
__global__ __launch_bounds__(256, 4) void out_kernel(
    const float* __restrict__ Q, const float* __restrict__ klm,
    const float* __restrict__ W, float* __restrict__ Out) {
  __shared__ alignas(16) short WtH[64*64], WtL[64*64];  // W^T planes (16 KB)
  __shared__ alignas(16) float Prow[64*MATP];           // P fp32 (17.4 KB)
  const int bh = blockIdx.y, b = bh >> 4, h = bh & 15;
  const int n0 = blockIdx.x * 64;
  const int tid = threadIdx.x;
  const int wid = tid >> 6, lane = tid & 63;
  const int lr = lane & 15, lg = lane >> 4;
  const int m0 = wid*16 + lg*4;

  const int dW = 4*lr + lg;
#pragma unroll
  for (int q = 0; q < 4; ++q) {
    int f = tid + 256*q;
    int r = f >> 4, c4 = (f & 15) << 2;
    float4 wv = *(const float4*)&W[(size_t)bh*4096 + r*64 + c4];
    float x[4] = {wv.x, wv.y, wv.z, wv.w};
    xpose4(x, lane);
    int nb = 16*q + 4*wid;
    s16x4 wh, wl; split4(x, wh, wl);
    int B = (dW << 7) + (nb << 1);
    B ^= (dW & 7) << 4;
    *(s16x4*)((char*)WtH + B) = wh;
    *(s16x4*)((char*)WtL + B) = wl;
  }

  bf16x8 qh[2], qlo[2];
#pragma unroll
  for (int ks = 0; ks < 2; ++ks) {
    const float* qp = Q + ((size_t)b*NN + n0 + wid*16 + lr)*CC + h*HD + ks*32 + lg*8;
    float qf[8];
    *(float4*)&qf[0] = *(const float4*)qp;
    *(float4*)&qf[4] = *(const float4*)(qp + 4);
#pragma unroll
    for (int i = 0; i < 8; ++i) qf[i] *= 0.125f;
    split8(qf, qh[ks], qlo[ks]);
  }

  // GEMM1: z[n][l] = sum_d Q[n][d] * klm[l][d]  (klm JIT from global, L2-resident)
  f32x4 zacc[4];
#pragma unroll
  for (int t = 0; t < 4; ++t) zacc[t] = (f32x4){0.f, 0.f, 0.f, 0.f};
#pragma unroll
  for (int tn = 0; tn < 4; ++tn) {
    const float* kp = &klm[(size_t)bh*4096 + (tn*16 + lr)*64 + lg*8];
    float4 k00 = *(const float4*)kp;
    float4 k01 = *(const float4*)(kp + 4);
    float4 k10 = *(const float4*)(kp + 32);
    float4 k11 = *(const float4*)(kp + 36);
    float kf[8];
    *(float4*)&kf[0] = k00; *(float4*)&kf[4] = k01;
    bf16x8 b0h, b0l; split8(kf, b0h, b0l);
    *(float4*)&kf[0] = k10; *(float4*)&kf[4] = k11;
    bf16x8 b1h, b1l; split8(kf, b1h, b1l);
    zacc[tn] = __builtin_amdgcn_mfma_f32_16x16x32_bf16(qh[0], b0h, zacc[tn], 0, 0, 0);
    zacc[tn] = __builtin_amdgcn_mfma_f32_16x16x32_bf16(qh[0], b0l, zacc[tn], 0, 0, 0);
    zacc[tn] = __builtin_amdgcn_mfma_f32_16x16x32_bf16(qlo[0], b0h, zacc[tn], 0, 0, 0);
    zacc[tn] = __builtin_amdgcn_mfma_f32_16x16x32_bf16(qh[1], b1h, zacc[tn], 0, 0, 0);
    zacc[tn] = __builtin_amdgcn_mfma_f32_16x16x32_bf16(qh[1], b1l, zacc[tn], 0, 0, 0);
    zacc[tn] = __builtin_amdgcn_mfma_f32_16x16x32_bf16(qlo[1], b1h, zacc[tn], 0, 0, 0);
  }
  float e[4][4];
#pragma unroll
  for (int tn = 0; tn < 4; ++tn)
#pragma unroll
    for (int r = 0; r < 4; ++r) e[tn][r] = __expf(zacc[tn][r]);
#pragma unroll
  for (int r = 0; r < 4; ++r) {
    float t = e[0][r] + e[1][r] + e[2][r] + e[3][r];
    t = shfl_sum16(t);
    float ri = 1.0f / t;
#pragma unroll
    for (int tn = 0; tn < 4; ++tn) e[tn][r] *= ri;
  }
#pragma unroll
  for (int tn = 0; tn < 4; ++tn) {
    const int n = tn*16 + lr;
#pragma unroll
    for (int r = 0; r < 4; ++r) Prow[(m0+r)*MATP + n] = e[tn][r];
  }
  __syncthreads();   // Wt visible

  f32x4 oacc[4];
#pragma unroll
  for (int t = 0; t < 4; ++t) oacc[t] = (f32x4){0.f, 0.f, 0.f, 0.f};
#pragma unroll
  for (int ks = 0; ks < 2; ++ks) {
    float fa[8];
    const float* ap = Prow + (wid*16 + lr)*MATP + ks*32 + lg*8;
    *(float4*)&fa[0] = *(const float4*)ap;
    *(float4*)&fa[4] = *(const float4*)(ap + 4);
    bf16x8 ah, al; split8(fa, ah, al);
#pragma unroll
    for (int tn = 0; tn < 4; ++tn) {
      bf16x8 bh_ = ldP(WtH, tn*16 + lr, 4*ks + lg);
      bf16x8 bl_ = ldP(WtL, tn*16 + lr, 4*ks + lg);
      oacc[tn] = __builtin_amdgcn_mfma_f32_16x16x32_bf16(ah, bh_, oacc[tn], 0, 0, 0);
      oacc[tn] = __builtin_amdgcn_mfma_f32_16x16x32_bf16(ah, bl_, oacc[tn], 0, 0, 0);
      oacc[tn] = __builtin_amdgcn_mfma_f32_16x16x32_bf16(al, bh_, oacc[tn], 0, 0, 0);
    }
  }
#pragma unroll
  for (int tn = 0; tn < 4; ++tn) {
    const int d = tn*16 + lr;
#pragma unroll
    for (int r = 0; r < 4; ++r)
      Out[((size_t)b*NN + n0 + m0 + r)*CC + h*HD + d] = oacc[tn][r];
  }
}

// ---------------- host ----------------
extern "C" void kernel_launch(void* const* d_in, const int* in_sizes, int n_in,
                              void* d_out, int out_size, void* d_ws, size_t ws_size,
                              hipStream_t stream) {
  const float* Q = (const float*)d_in[0];
  const float* K = (const float*)d_in[1];
  const float* V = (const float*)d_in[2];
  float* out = (float*)d_out;
  float* ws  = (float*)d_ws;

  float* qlm   = ws;                // 262144 floats
  float* klm   = ws + 262144;       // 262144
  float* S3    = ws + 524288;       // 4096
  float* ACC3  = ws + 528384;       // 262144
  float* Wm    = ws + 790528;       // 262144
  float* ACC3p = ws + 1052672;      // 32*64*4160 = 8,519,680 floats (~34 MB)

  size_t shC = (size_t)(7*MATE + 384)*sizeof(float);   // ~123 KB
  hipFuncSetAttribute((const void*)inv_kernel,
                      hipFuncAttributeMaxDynamicSharedMemorySize, (int)shC);

  lm_kernel    <<<dim3(16, BHN), 256, 0, stream>>>(Q, K, qlm, klm);
  k3v_kernel   <<<dim3(NTILE, BHN), 256, 0, stream>>>(K, V, qlm, ACC3p);
  reduce_kernel<<<dim3(5, BHN), 256, 0, stream>>>(ACC3p, ACC3, S3);
  inv_kernel   <<<dim3(BHN),    1024, shC, stream>>>(qlm, klm, S3, ACC3, Wm);
  out_kernel   <<<dim3(64, BHN), 256, 0, stream>>>(Q, klm, Wm, out);
}